// Round 6
// baseline (58.942 us; speedup 1.0000x reference)
//
#include <hip/hip_runtime.h>
#include <hip/hip_cooperative_groups.h>

namespace cg = cooperative_groups;

// out = 2 * circconv(d, b),  d = des@K, b = body@K  (circ matvec is commutative)
//
// ONE cooperative kernel, grid 256 x 512 (1 block/CU, co-resident):
//  phase 1: block (rt,ct) computes final 32x32 tile of P=[d;b] (fp32, ws, 1 MB),
//           full K=1024 via 2 LDS rounds, bf16 MFMA 16x16x32, fragment-linear LDS
//           (layout verified in R5), cross-wave reduce in padded LDS.
//  grid.sync()
//  phase 2: block (r, k-half): 2 j-halves x 256 k-pairs, rolling-window conv
//           (R5 core), intra-block reduce, store 2*acc to out.

using bf16x8 = __attribute__((ext_vector_type(8))) short;
using f32x4  = __attribute__((ext_vector_type(4))) float;

static __device__ __forceinline__ unsigned short f2bf(float x) {
    union { float f; unsigned u; } v; v.f = x;
    return (unsigned short)((v.u + 0x7FFFu + ((v.u >> 16) & 1u)) >> 16);
}
static __device__ __forceinline__ unsigned pack2(float x, float y) {
    return (unsigned)f2bf(x) | ((unsigned)f2bf(y) << 16);
}

__global__ __launch_bounds__(512) void fused_kernel(
    const float* __restrict__ des, const float* __restrict__ body,
    const float* __restrict__ kmat, float* __restrict__ P,
    float* __restrict__ out)
{
    __shared__ float smemf[16384];            // 64 KB, aliased per phase
    short* Al = (short*)smemf;                // 32 KB: 2048 x 16B units
    short* Bl = (short*)(smemf + 8192);       // 32 KB
    float* Rbuf = smemf;                      // 8 x 32 x 36 fp32 = 36 KB (reuse)

    const int tid = threadIdx.x;
    const int bid = blockIdx.x;
    const int lane = tid & 63;
    const int wid = tid >> 6;                 // 8 waves

    // ---------------- phase 1: GEMM -> P ----------------
    const int rt = bid >> 5;                  // 8 row-tiles of 32 virtual rows
    const int ct = bid & 31;                  // 32 col-tiles of 32 cols
    const int R0 = rt * 32, C0 = ct * 32;
    const float* Asrc = (R0 < 128) ? (des + (size_t)R0 * 1024)
                                   : (body + (size_t)(R0 - 128) * 1024);

    f32x4 acc[2][2];
    #pragma unroll
    for (int i = 0; i < 2; ++i)
        #pragma unroll
        for (int j = 0; j < 2; ++j) acc[i][j] = (f32x4){0.f, 0.f, 0.f, 0.f};

    // LDS fragment-linear (verified R5 pattern), per 512-k round:
    //   A unit(r,k) = ((r>>4)*16 + (k>>5))*64 + ((k>>3)&3)*16 + (r&15)
    //   B unit(k,c) = ((c>>4)*16 + (k>>5))*64 + ((k>>3)&3)*16 + (c&15)
    // byte-within-unit = (k&7)*2; wave w uses kchunks {2w, 2w+1}.
    #pragma unroll 1
    for (int round = 0; round < 2; ++round) {
        const int kb = round * 512;
        // stage A: 32 rows x 512 k = 1024 float4, 8 per thread (coalesced)
        #pragma unroll
        for (int i = 0; i < 8; ++i) {
            int t4 = tid + i * 512;
            int c4 = t4 & 127, r = t4 >> 7;
            float4 F = *(const float4*)(Asrc + (size_t)r * 1024 + kb + c4 * 4);
            int k = c4 * 4;
            int unit = ((r >> 4) * 16 + (k >> 5)) * 64 + ((k >> 3) & 3) * 16 + (r & 15);
            *(uint2*)(Al + unit * 8 + (k & 7)) = make_uint2(pack2(F.x, F.y), pack2(F.z, F.w));
        }
        // stage B: 512 k x 32 cols; task (ke2 0..255, c4 0..7), 4 per thread
        #pragma unroll
        for (int i = 0; i < 4; ++i) {
            int t4 = tid + i * 512;
            int c4 = t4 & 7, ke2 = t4 >> 3;
            int k = ke2 * 2;
            float4 Fa = *(const float4*)(kmat + (size_t)(kb + k) * 1024 + C0 + c4 * 4);
            float4 Fb = *(const float4*)(kmat + (size_t)(kb + k + 1) * 1024 + C0 + c4 * 4);
            const float fa[4] = {Fa.x, Fa.y, Fa.z, Fa.w};
            const float fb[4] = {Fb.x, Fb.y, Fb.z, Fb.w};
            #pragma unroll
            for (int u = 0; u < 4; ++u) {
                int c = c4 * 4 + u;
                int unit = ((c >> 4) * 16 + (k >> 5)) * 64 + ((k >> 3) & 3) * 16 + (c & 15);
                *(unsigned*)(Bl + unit * 8 + (k & 7)) = pack2(fa[u], fb[u]);
            }
        }
        __syncthreads();
        #pragma unroll
        for (int s = 0; s < 2; ++s) {
            int kc = wid * 2 + s;
            bf16x8 a0 = *(const bf16x8*)(Al + ((0 * 16 + kc) * 64 + lane) * 8);
            bf16x8 a1 = *(const bf16x8*)(Al + ((1 * 16 + kc) * 64 + lane) * 8);
            bf16x8 b0 = *(const bf16x8*)(Bl + ((0 * 16 + kc) * 64 + lane) * 8);
            bf16x8 b1 = *(const bf16x8*)(Bl + ((1 * 16 + kc) * 64 + lane) * 8);
            // swapped operands (verified): lane holds row=lane&15, 4 regs = cols
            acc[0][0] = __builtin_amdgcn_mfma_f32_16x16x32_bf16(b0, a0, acc[0][0], 0, 0, 0);
            acc[0][1] = __builtin_amdgcn_mfma_f32_16x16x32_bf16(b1, a0, acc[0][1], 0, 0, 0);
            acc[1][0] = __builtin_amdgcn_mfma_f32_16x16x32_bf16(b0, a1, acc[1][0], 0, 0, 0);
            acc[1][1] = __builtin_amdgcn_mfma_f32_16x16x32_bf16(b1, a1, acc[1][1], 0, 0, 0);
        }
        __syncthreads();
    }

    // cross-wave reduce: write per-wave 32x32 tiles (stride-36 pad, 2-way max)
    #pragma unroll
    for (int rg = 0; rg < 2; ++rg)
        #pragma unroll
        for (int cgi = 0; cgi < 2; ++cgi) {
            int r = rg * 16 + (lane & 15);
            int c = cgi * 16 + ((lane >> 4) << 2);
            *(f32x4*)&Rbuf[wid * 1152 + r * 36 + c] = acc[rg][cgi];
        }
    __syncthreads();
    {
        int o = tid * 2;
        int r = o >> 5, c = o & 31;
        float2 s = make_float2(0.f, 0.f);
        #pragma unroll
        for (int w = 0; w < 8; ++w) {
            float2 v = *(const float2*)&Rbuf[w * 1152 + r * 36 + c];
            s.x += v.x; s.y += v.y;
        }
        *(float2*)(P + (size_t)(R0 + r) * 1024 + C0 + c) = s;
    }

    cg::this_grid().sync();

    // ---------------- phase 2: conv -> out ----------------
    float* dl = smemf;                        // 1024 f32
    float* bl = smemf + 1024;                 // 1024 f32
    float2* red = (float2*)(smemf + 2048);    // 512 float2

    const int r2 = bid >> 1;                  // row 0..127
    const int kh = bid & 1;                   // k-half

    if (tid < 256)
        ((float4*)dl)[tid] = *((const float4*)(P + (size_t)r2 * 1024) + tid);
    else
        ((float4*)bl)[tid - 256] = *((const float4*)(P + (size_t)(128 + r2) * 1024) + (tid - 256));
    __syncthreads();

    const int jbase = (tid >> 8) * 512;       // 0 or 512
    const int p = tid & 255;                  // k-pair
    const int k0 = (kh * 512 + p * 2 - jbase) & 1023;

    float a0a = 0.f, a0b = 0.f, a1a = 0.f, a1b = 0.f;
    float2 W2 = *(const float2*)&dl[k0];

    for (int jc = 0; jc < 512; jc += 8) {
        float4 bv0 = *(const float4*)&bl[jbase + jc];
        float2 W0  = *(const float2*)&dl[(k0 - jc - 4) & 1023];
        float2 W1  = *(const float2*)&dl[(k0 - jc - 2) & 1023];
        a0a += bv0.x * W2.x + bv0.y * W1.y + bv0.z * W1.x + bv0.w * W0.y;
        a1a += bv0.x * W2.y + bv0.y * W2.x + bv0.z * W1.y + bv0.w * W1.x;

        float4 bv1 = *(const float4*)&bl[jbase + jc + 4];
        float2 V0  = *(const float2*)&dl[(k0 - jc - 8) & 1023];
        float2 V1  = *(const float2*)&dl[(k0 - jc - 6) & 1023];
        a0b += bv1.x * W0.x + bv1.y * V1.y + bv1.z * V1.x + bv1.w * V0.y;
        a1b += bv1.x * W0.y + bv1.y * W0.x + bv1.z * V1.y + bv1.w * V1.x;

        W2 = V0;
    }

    red[tid] = make_float2(a0a + a0b, a1a + a1b);
    __syncthreads();
    if (tid < 256) {
        float2 x = red[tid], y = red[tid + 256];
        *(float2*)(out + (size_t)r2 * 1024 + kh * 512 + tid * 2) =
            make_float2(2.f * (x.x + y.x), 2.f * (x.y + y.y));
    }
}

extern "C" void kernel_launch(void* const* d_in, const int* in_sizes, int n_in,
                              void* d_out, int out_size, void* d_ws, size_t ws_size,
                              hipStream_t stream) {
    const float* des  = (const float*)d_in[0];
    const float* body = (const float*)d_in[1];
    const float* kmat = (const float*)d_in[2];
    float* P = (float*)d_ws;          // 256*1024 fp32 = 1 MB
    float* o = (float*)d_out;

    void* args[] = {(void*)&des, (void*)&body, (void*)&kmat, (void*)&P, (void*)&o};
    hipLaunchCooperativeKernel((const void*)fused_kernel, dim3(256), dim3(512),
                               args, 0, stream);
}

// Round 7
// 23.981 us; speedup vs baseline: 2.4578x; 2.4578x over previous
//
#include <hip/hip_runtime.h>

// out = 2 * circconv(d, b),  d = des@K, b = body@K  (circ matvec is commutative)
//
// k1 gemm: grid 256 (8 row-bands x 32 col-bands), block 512 (8 waves).
//          Each block -> final fp32 32x32 tile of P=[d;b], full K=1024.
//          Waves split K (4 k-chunks of 32 each over 2 rounds); A operands
//          direct global->reg (bf16 via v_cvt_pk); B staged in LDS with XOR
//          slot swizzle (write & read same involution); cross-wave LDS reduce.
// k2 conv: grid 512 (128 rows x 4 k-quarters), block 256 (2 j-halves x 128
//          k-pairs). Rolling float2-window core (verified R3/R5/R6); pair
//          reduce in LDS; direct store 2*acc.

using bf16x8 = __attribute__((ext_vector_type(8))) short;
using f32x4  = __attribute__((ext_vector_type(4))) float;

static __device__ __forceinline__ unsigned cvt_pk_bf16(float lo, float hi) {
    unsigned r;
    asm("v_cvt_pk_bf16_f32 %0, %1, %2" : "=v"(r) : "v"(lo), "v"(hi));
    return r;
}

__global__ __launch_bounds__(512) void gemm_kernel(
    const float* __restrict__ des, const float* __restrict__ body,
    const float* __restrict__ kmat, float* __restrict__ P)
{
    // Bl: 2048 units x 16B = 32 KB (bf16 512k x 32c, fragment-linear+swizzle)
    // Rbuf: 8 waves x 32 x 36 fp32 = 36 KB, aliases Bl after last MFMA round
    __shared__ float smem[9216];
    short* Bl = (short*)smem;
    float* Rbuf = smem;

    const int tid = threadIdx.x;
    const int bid = blockIdx.x;
    const int rt = bid >> 5;           // row band (32 virtual rows)
    const int ct = bid & 31;           // col band (32 cols)
    const int R0 = rt * 32, C0 = ct * 32;
    const float* Arow = (R0 < 128) ? (des + (size_t)R0 * 1024)
                                   : (body + (size_t)(R0 - 128) * 1024);

    const int lane = tid & 63;
    const int w = tid >> 6;            // wave 0..7
    const int lr = lane & 15;          // fragment row slot
    const int lk = lane >> 4;          // fragment k-group (8 k each)

    f32x4 acc[2][2];
    #pragma unroll
    for (int q = 0; q < 2; ++q)
        #pragma unroll
        for (int g = 0; g < 2; ++g) acc[q][g] = (f32x4){0.f, 0.f, 0.f, 0.f};

    #pragma unroll 1
    for (int round = 0; round < 2; ++round) {
        const int kb = round * 512;

        // ---- stage B: 512k x 32c -> LDS bf16, fragment-linear + XOR swizzle.
        // unit(k,c) = ((c>>4)*16 + (k>>5))*64 + ((k>>3)&3)*16 + ((c&15) ^ ((k>>3)&7))
        // dword slot (k even): shorts (k&7), holds bf16(k), bf16(k+1).
        #pragma unroll
        for (int i = 0; i < 4; ++i) {
            int t4 = tid + i * 512;            // 2048 tasks
            int ke2 = t4 >> 3, c4 = t4 & 7;    // 256 k-pairs x 8 col-quads
            int k = ke2 * 2;
            const float* src = kmat + (size_t)(kb + k) * 1024 + C0 + c4 * 4;
            float4 Fa = *(const float4*)src;
            float4 Fb = *(const float4*)(src + 1024);
            const float fa[4] = {Fa.x, Fa.y, Fa.z, Fa.w};
            const float fb[4] = {Fb.x, Fb.y, Fb.z, Fb.w};
            int kg = (k >> 3) & 3, kc = k >> 5, sw = (k >> 3) & 7;
            #pragma unroll
            for (int u = 0; u < 4; ++u) {
                int c = c4 * 4 + u;
                int unit = (((c >> 4) * 16 + kc) << 6) + (kg << 4) + ((c & 15) ^ sw);
                *(unsigned*)&Bl[unit * 8 + (k & 7)] = cvt_pk_bf16(fa[u], fb[u]);
            }
        }
        __syncthreads();

        // ---- MFMA: wave w covers k-chunks {2w, 2w+1} of this round
        #pragma unroll
        for (int s = 0; s < 2; ++s) {
            const int kc = w * 2 + s;
            const int kglob = kb + kc * 32 + lk * 8;

            bf16x8 afr[2];
            #pragma unroll
            for (int q = 0; q < 2; ++q) {
                const float* ap = Arow + (size_t)(q * 16 + lr) * 1024 + kglob;
                float4 F0 = *(const float4*)ap;
                float4 F1 = *(const float4*)(ap + 4);
                uint4 ua;
                ua.x = cvt_pk_bf16(F0.x, F0.y);
                ua.y = cvt_pk_bf16(F0.z, F0.w);
                ua.z = cvt_pk_bf16(F1.x, F1.y);
                ua.w = cvt_pk_bf16(F1.z, F1.w);
                afr[q] = *(bf16x8*)&ua;
            }
            const int slot = lr ^ ((kc * 4 + lk) & 7);
            #pragma unroll
            for (int g = 0; g < 2; ++g) {
                int unit = ((g * 16 + kc) << 6) + (lk << 4) + slot;
                bf16x8 bfr = *(const bf16x8*)&Bl[unit * 8];
                // swapped operands (verified R5): lane row = lr, 4 regs = cols
                acc[0][g] = __builtin_amdgcn_mfma_f32_16x16x32_bf16(bfr, afr[0], acc[0][g], 0, 0, 0);
                acc[1][g] = __builtin_amdgcn_mfma_f32_16x16x32_bf16(bfr, afr[1], acc[1][g], 0, 0, 0);
            }
        }
        __syncthreads();
    }

    // ---- cross-wave reduce (Rbuf aliases Bl; sync above guards reuse)
    #pragma unroll
    for (int q = 0; q < 2; ++q)
        #pragma unroll
        for (int g = 0; g < 2; ++g) {
            int r = q * 16 + lr;
            int c = g * 16 + (lk << 2);
            *(f32x4*)&Rbuf[w * 1152 + r * 36 + c] = acc[q][g];
        }
    __syncthreads();
    {
        int o = tid * 2;                 // 1024 outputs
        int r = o >> 5, c = o & 31;
        float2 s = make_float2(0.f, 0.f);
        #pragma unroll
        for (int u = 0; u < 8; ++u) {
            float2 v = *(const float2*)&Rbuf[u * 1152 + r * 36 + c];
            s.x += v.x; s.y += v.y;
        }
        *(float2*)(P + (size_t)(R0 + r) * 1024 + C0 + c) = s;
    }
}

__global__ __launch_bounds__(256) void conv_kernel(
    const float* __restrict__ P, float* __restrict__ out)
{
    __shared__ float dl[1024];
    __shared__ float bl[1024];
    __shared__ float2 red[256];

    const int tid = threadIdx.x;
    const int bid = blockIdx.x;
    const int r = bid >> 2;            // row 0..127
    const int kq = bid & 3;            // k-quarter

    ((float4*)dl)[tid] = ((const float4*)(P + (size_t)r * 1024))[tid];
    ((float4*)bl)[tid] = ((const float4*)(P + (size_t)(128 + r) * 1024))[tid];
    __syncthreads();

    const int jh = tid >> 7;           // j-half
    const int p = tid & 127;           // k-pair within quarter
    const int jbase = jh * 512;
    const int k0 = (kq * 256 + p * 2 - jbase) & 1023;   // even

    float a0a = 0.f, a0b = 0.f, a1a = 0.f, a1b = 0.f;
    float2 W2 = *(const float2*)&dl[k0];

    for (int jc = 0; jc < 512; jc += 8) {
        float4 bv0 = *(const float4*)&bl[jbase + jc];
        float2 W0  = *(const float2*)&dl[(k0 - jc - 4) & 1023];
        float2 W1  = *(const float2*)&dl[(k0 - jc - 2) & 1023];
        a0a += bv0.x * W2.x + bv0.y * W1.y + bv0.z * W1.x + bv0.w * W0.y;
        a1a += bv0.x * W2.y + bv0.y * W2.x + bv0.z * W1.y + bv0.w * W1.x;

        float4 bv1 = *(const float4*)&bl[jbase + jc + 4];
        float2 V0  = *(const float2*)&dl[(k0 - jc - 8) & 1023];
        float2 V1  = *(const float2*)&dl[(k0 - jc - 6) & 1023];
        a0b += bv1.x * W0.x + bv1.y * V1.y + bv1.z * V1.x + bv1.w * V0.y;
        a1b += bv1.x * W0.y + bv1.y * W0.x + bv1.z * V1.y + bv1.w * V1.x;

        W2 = V0;
    }

    red[tid] = make_float2(a0a + a0b, a1a + a1b);
    __syncthreads();
    if (tid < 128) {
        float2 x = red[tid], y = red[tid + 128];
        *(float2*)(out + (size_t)r * 1024 + kq * 256 + tid * 2) =
            make_float2(2.f * (x.x + y.x), 2.f * (x.y + y.y));
    }
}

extern "C" void kernel_launch(void* const* d_in, const int* in_sizes, int n_in,
                              void* d_out, int out_size, void* d_ws, size_t ws_size,
                              hipStream_t stream) {
    const float* des  = (const float*)d_in[0];
    const float* body = (const float*)d_in[1];
    const float* kmat = (const float*)d_in[2];
    float* P = (float*)d_ws;   // 256*1024 fp32 = 1 MB

    gemm_kernel<<<256, 512, 0, stream>>>(des, body, kmat, P);
    conv_kernel<<<512, 256, 0, stream>>>(P, (float*)d_out);
}

// Round 8
// 20.059 us; speedup vs baseline: 2.9384x; 1.1955x over previous
//
#include <hip/hip_runtime.h>

// out = 2 * circconv(d, b),  d = des@K, b = body@K  (circ matvec is commutative)
//
// k1 gemm (UNCHANGED from R7): grid 256, block 512; fp32 32x32 tile of P=[d;b],
//          full K=1024; A global->reg bf16, B in swizzled LDS; cross-wave reduce.
// k2 conv (REWRITTEN): grid 256 (128 rows x 2 k-halves), block 256 (4 waves =
//          4 j-quarters). 8 outputs/thread, rolling float4 window (R1 core):
//          2 LDS reads + 32 FMA per 4 j  (was 6 reads + 16 FMA per 8 j).
//          dl XOR f4-slot swizzle kills the 32B-stride bank conflicts.

using bf16x8 = __attribute__((ext_vector_type(8))) short;
using f32x4  = __attribute__((ext_vector_type(4))) float;

static __device__ __forceinline__ unsigned cvt_pk_bf16(float lo, float hi) {
    unsigned r;
    asm("v_cvt_pk_bf16_f32 %0, %1, %2" : "=v"(r) : "v"(lo), "v"(hi));
    return r;
}

__global__ __launch_bounds__(512) void gemm_kernel(
    const float* __restrict__ des, const float* __restrict__ body,
    const float* __restrict__ kmat, float* __restrict__ P)
{
    __shared__ float smem[9216];
    short* Bl = (short*)smem;
    float* Rbuf = smem;

    const int tid = threadIdx.x;
    const int bid = blockIdx.x;
    const int rt = bid >> 5;
    const int ct = bid & 31;
    const int R0 = rt * 32, C0 = ct * 32;
    const float* Arow = (R0 < 128) ? (des + (size_t)R0 * 1024)
                                   : (body + (size_t)(R0 - 128) * 1024);

    const int lane = tid & 63;
    const int w = tid >> 6;
    const int lr = lane & 15;
    const int lk = lane >> 4;

    f32x4 acc[2][2];
    #pragma unroll
    for (int q = 0; q < 2; ++q)
        #pragma unroll
        for (int g = 0; g < 2; ++g) acc[q][g] = (f32x4){0.f, 0.f, 0.f, 0.f};

    #pragma unroll 1
    for (int round = 0; round < 2; ++round) {
        const int kb = round * 512;
        #pragma unroll
        for (int i = 0; i < 4; ++i) {
            int t4 = tid + i * 512;
            int ke2 = t4 >> 3, c4 = t4 & 7;
            int k = ke2 * 2;
            const float* src = kmat + (size_t)(kb + k) * 1024 + C0 + c4 * 4;
            float4 Fa = *(const float4*)src;
            float4 Fb = *(const float4*)(src + 1024);
            const float fa[4] = {Fa.x, Fa.y, Fa.z, Fa.w};
            const float fb[4] = {Fb.x, Fb.y, Fb.z, Fb.w};
            int kg = (k >> 3) & 3, kc = k >> 5, sw = (k >> 3) & 7;
            #pragma unroll
            for (int u = 0; u < 4; ++u) {
                int c = c4 * 4 + u;
                int unit = (((c >> 4) * 16 + kc) << 6) + (kg << 4) + ((c & 15) ^ sw);
                *(unsigned*)&Bl[unit * 8 + (k & 7)] = cvt_pk_bf16(fa[u], fb[u]);
            }
        }
        __syncthreads();

        #pragma unroll
        for (int s = 0; s < 2; ++s) {
            const int kc = w * 2 + s;
            const int kglob = kb + kc * 32 + lk * 8;

            bf16x8 afr[2];
            #pragma unroll
            for (int q = 0; q < 2; ++q) {
                const float* ap = Arow + (size_t)(q * 16 + lr) * 1024 + kglob;
                float4 F0 = *(const float4*)ap;
                float4 F1 = *(const float4*)(ap + 4);
                uint4 ua;
                ua.x = cvt_pk_bf16(F0.x, F0.y);
                ua.y = cvt_pk_bf16(F0.z, F0.w);
                ua.z = cvt_pk_bf16(F1.x, F1.y);
                ua.w = cvt_pk_bf16(F1.z, F1.w);
                afr[q] = *(bf16x8*)&ua;
            }
            const int slot = lr ^ ((kc * 4 + lk) & 7);
            #pragma unroll
            for (int g = 0; g < 2; ++g) {
                int unit = ((g * 16 + kc) << 6) + (lk << 4) + slot;
                bf16x8 bfr = *(const bf16x8*)&Bl[unit * 8];
                acc[0][g] = __builtin_amdgcn_mfma_f32_16x16x32_bf16(bfr, afr[0], acc[0][g], 0, 0, 0);
                acc[1][g] = __builtin_amdgcn_mfma_f32_16x16x32_bf16(bfr, afr[1], acc[1][g], 0, 0, 0);
            }
        }
        __syncthreads();
    }

    #pragma unroll
    for (int q = 0; q < 2; ++q)
        #pragma unroll
        for (int g = 0; g < 2; ++g) {
            int r = q * 16 + lr;
            int c = g * 16 + (lk << 2);
            *(f32x4*)&Rbuf[w * 1152 + r * 36 + c] = acc[q][g];
        }
    __syncthreads();
    {
        int o = tid * 2;
        int r = o >> 5, c = o & 31;
        float2 s = make_float2(0.f, 0.f);
        #pragma unroll
        for (int u = 0; u < 8; ++u) {
            float2 v = *(const float2*)&Rbuf[u * 1152 + r * 36 + c];
            s.x += v.x; s.y += v.y;
        }
        *(float2*)(P + (size_t)(R0 + r) * 1024 + C0 + c) = s;
    }
}

__global__ __launch_bounds__(256) void conv_kernel(
    const float* __restrict__ P, float* __restrict__ out)
{
    __shared__ float dl[1024];     // XOR f4-slot swizzled
    __shared__ float bl[1024];     // linear (broadcast reads only)
    __shared__ float red[2304];    // 4 jq x 64 t x 9 (pad)

    const int tid = threadIdx.x;
    const int bid = blockIdx.x;
    const int r = bid >> 1;        // row 0..127
    const int h = bid & 1;         // k-half

    {
        int sw = tid ^ ((tid >> 3) & 7);
        ((float4*)dl)[sw]  = ((const float4*)(P + (size_t)r * 1024))[tid];
        ((float4*)bl)[tid] = ((const float4*)(P + (size_t)(128 + r) * 1024))[tid];
    }
    __syncthreads();

    const int jq = tid >> 6;       // wave index = j-quarter (bv stays uniform)
    const int t  = tid & 63;       // k-octet
    const int k0 = (h * 512 + t * 8 - jq * 256) & 1023;   // multiple of 8

    // swizzled float4 read at float index fidx (multiple of 4, pre-masked)
#define RD(fidx) (((const float4*)dl)[(((fidx) >> 2) ^ ((((fidx) >> 2) >> 3) & 7))])

    float acc[8] = {0.f, 0.f, 0.f, 0.f, 0.f, 0.f, 0.f, 0.f};
    float4 A  = RD(k0);
    float4 Bv = RD((k0 + 4) & 1023);

    const float* bq = bl + jq * 256;
    #pragma unroll 4
    for (int jc = 0; jc < 256; jc += 4) {
        float4 bv = *(const float4*)&bq[jc];           // wave-uniform broadcast
        float4 Nv = RD((k0 - jc - 4) & 1023);
        // R1-verified pattern: idx = base + q - s, base = k0 - jc
        acc[0] += bv.x * A.x;  acc[1] += bv.x * A.y;  acc[2] += bv.x * A.z;  acc[3] += bv.x * A.w;
        acc[4] += bv.x * Bv.x; acc[5] += bv.x * Bv.y; acc[6] += bv.x * Bv.z; acc[7] += bv.x * Bv.w;
        acc[0] += bv.y * Nv.w; acc[1] += bv.y * A.x;  acc[2] += bv.y * A.y;  acc[3] += bv.y * A.z;
        acc[4] += bv.y * A.w;  acc[5] += bv.y * Bv.x; acc[6] += bv.y * Bv.y; acc[7] += bv.y * Bv.z;
        acc[0] += bv.z * Nv.z; acc[1] += bv.z * Nv.w; acc[2] += bv.z * A.x;  acc[3] += bv.z * A.y;
        acc[4] += bv.z * A.z;  acc[5] += bv.z * A.w;  acc[6] += bv.z * Bv.x; acc[7] += bv.z * Bv.y;
        acc[0] += bv.w * Nv.y; acc[1] += bv.w * Nv.z; acc[2] += bv.w * Nv.w; acc[3] += bv.w * A.x;
        acc[4] += bv.w * A.y;  acc[5] += bv.w * A.z;  acc[6] += bv.w * A.w;  acc[7] += bv.w * Bv.x;
        Bv = A; A = Nv;
    }
#undef RD

    {
        float* rd = red + jq * 576 + t * 9;
        #pragma unroll
        for (int q = 0; q < 8; ++q) rd[q] = acc[q];
    }
    __syncthreads();
    {
        int t2 = tid >> 2, qb = (tid & 3) * 2;    // output pair o = tid*2
        float s0 = 0.f, s1 = 0.f;
        #pragma unroll
        for (int u = 0; u < 4; ++u) {
            s0 += red[u * 576 + t2 * 9 + qb];
            s1 += red[u * 576 + t2 * 9 + qb + 1];
        }
        *(float2*)(out + (size_t)r * 1024 + h * 512 + tid * 2) =
            make_float2(2.f * s0, 2.f * s1);
    }
}

extern "C" void kernel_launch(void* const* d_in, const int* in_sizes, int n_in,
                              void* d_out, int out_size, void* d_ws, size_t ws_size,
                              hipStream_t stream) {
    const float* des  = (const float*)d_in[0];
    const float* body = (const float*)d_in[1];
    const float* kmat = (const float*)d_in[2];
    float* P = (float*)d_ws;   // 256*1024 fp32 = 1 MB

    gemm_kernel<<<256, 512, 0, stream>>>(des, body, kmat, P);
    conv_kernel<<<256, 256, 0, stream>>>(P, (float*)d_out);
}

// Round 9
// 17.846 us; speedup vs baseline: 3.3027x; 1.1240x over previous
//
#include <hip/hip_runtime.h>

// out = 2 * circconv(d, b),  d = des@K, b = body@K  (circ matvec is commutative)
//
// k1 gemm: grid 512 (8 rt x 32 ct x 2 kh), block 512 (8 waves) -> 2 blocks/CU,
//          4 waves/SIMD. Each block: one K-half (512 k) of a fp32 32x32 tile,
//          single stage/sync/MFMA pass (R8 round body), cross-wave reduce,
//          write to Ppart[kh] (2 x 1 MB fp32, no atomics).
// k2 conv: grid 256 (128 rows x 2 k-halves), block 512 (8 waves = 8 j-eighths,
//          2 waves/SIMD). Staging sums Ppart[0]+Ppart[1]. Rolling float4-window
//          core (R8-verified), 32 iters/thread, 8-way padded-LDS reduce.

using bf16x8 = __attribute__((ext_vector_type(8))) short;
using f32x4  = __attribute__((ext_vector_type(4))) float;

static __device__ __forceinline__ unsigned cvt_pk_bf16(float lo, float hi) {
    unsigned r;
    asm("v_cvt_pk_bf16_f32 %0, %1, %2" : "=v"(r) : "v"(lo), "v"(hi));
    return r;
}

__global__ __launch_bounds__(512) void gemm_kernel(
    const float* __restrict__ des, const float* __restrict__ body,
    const float* __restrict__ kmat, float* __restrict__ Ppart)
{
    __shared__ float smem[9216];     // 36 KB: Bl (32 KB) then Rbuf (36 KB)
    short* Bl = (short*)smem;
    float* Rbuf = smem;

    const int tid = threadIdx.x;
    const int bid = blockIdx.x;
    const int kh = bid & 1;            // K-half
    const int ct = (bid >> 1) & 31;    // col band (32 cols)
    const int rt = bid >> 6;           // row band (32 virtual rows)
    const int R0 = rt * 32, C0 = ct * 32;
    const int kb = kh * 512;
    const float* Arow = (R0 < 128) ? (des + (size_t)R0 * 1024)
                                   : (body + (size_t)(R0 - 128) * 1024);

    const int lane = tid & 63;
    const int w = tid >> 6;            // wave 0..7 -> k-chunks {2w, 2w+1}
    const int lr = lane & 15;
    const int lk = lane >> 4;

    f32x4 acc[2][2];
    #pragma unroll
    for (int q = 0; q < 2; ++q)
        #pragma unroll
        for (int g = 0; g < 2; ++g) acc[q][g] = (f32x4){0.f, 0.f, 0.f, 0.f};

    // stage B: 512k x 32c bf16, fragment-linear + XOR slot swizzle (R7-verified)
    #pragma unroll
    for (int i = 0; i < 4; ++i) {
        int t4 = tid + i * 512;
        int ke2 = t4 >> 3, c4 = t4 & 7;
        int k = ke2 * 2;
        const float* src = kmat + (size_t)(kb + k) * 1024 + C0 + c4 * 4;
        float4 Fa = *(const float4*)src;
        float4 Fb = *(const float4*)(src + 1024);
        const float fa[4] = {Fa.x, Fa.y, Fa.z, Fa.w};
        const float fb[4] = {Fb.x, Fb.y, Fb.z, Fb.w};
        int kg = (k >> 3) & 3, kc = k >> 5, sw = (k >> 3) & 7;
        #pragma unroll
        for (int u = 0; u < 4; ++u) {
            int c = c4 * 4 + u;
            int unit = (((c >> 4) * 16 + kc) << 6) + (kg << 4) + ((c & 15) ^ sw);
            *(unsigned*)&Bl[unit * 8 + (k & 7)] = cvt_pk_bf16(fa[u], fb[u]);
        }
    }
    __syncthreads();

    #pragma unroll
    for (int s = 0; s < 2; ++s) {
        const int kc = w * 2 + s;
        const int kglob = kb + kc * 32 + lk * 8;

        bf16x8 afr[2];
        #pragma unroll
        for (int q = 0; q < 2; ++q) {
            const float* ap = Arow + (size_t)(q * 16 + lr) * 1024 + kglob;
            float4 F0 = *(const float4*)ap;
            float4 F1 = *(const float4*)(ap + 4);
            uint4 ua;
            ua.x = cvt_pk_bf16(F0.x, F0.y);
            ua.y = cvt_pk_bf16(F0.z, F0.w);
            ua.z = cvt_pk_bf16(F1.x, F1.y);
            ua.w = cvt_pk_bf16(F1.z, F1.w);
            afr[q] = *(bf16x8*)&ua;
        }
        const int slot = lr ^ ((kc * 4 + lk) & 7);
        #pragma unroll
        for (int g = 0; g < 2; ++g) {
            int unit = ((g * 16 + kc) << 6) + (lk << 4) + slot;
            bf16x8 bfr = *(const bf16x8*)&Bl[unit * 8];
            // swapped operands (R5-verified): lane row = lr, 4 regs = cols
            acc[0][g] = __builtin_amdgcn_mfma_f32_16x16x32_bf16(bfr, afr[0], acc[0][g], 0, 0, 0);
            acc[1][g] = __builtin_amdgcn_mfma_f32_16x16x32_bf16(bfr, afr[1], acc[1][g], 0, 0, 0);
        }
    }
    __syncthreads();

    // cross-wave reduce in padded LDS (aliases Bl)
    #pragma unroll
    for (int q = 0; q < 2; ++q)
        #pragma unroll
        for (int g = 0; g < 2; ++g) {
            int r = q * 16 + lr;
            int c = g * 16 + (lk << 2);
            *(f32x4*)&Rbuf[w * 1152 + r * 36 + c] = acc[q][g];
        }
    __syncthreads();
    {
        int o = tid * 2;
        int r = o >> 5, c = o & 31;
        float2 s = make_float2(0.f, 0.f);
        #pragma unroll
        for (int u = 0; u < 8; ++u) {
            float2 v = *(const float2*)&Rbuf[u * 1152 + r * 36 + c];
            s.x += v.x; s.y += v.y;
        }
        *(float2*)(Ppart + (size_t)kh * 262144 + (size_t)(R0 + r) * 1024 + C0 + c) = s;
    }
}

__global__ __launch_bounds__(512) void conv_kernel(
    const float* __restrict__ Ppart, float* __restrict__ out)
{
    __shared__ float dl[1024];     // XOR f4-slot swizzled
    __shared__ float bl[1024];     // linear (broadcast reads only)
    __shared__ float red[4608];    // 8 jo x 64 t x 9 (pad) = 18 KB

    const int tid = threadIdx.x;
    const int bid = blockIdx.x;
    const int r = bid >> 1;        // row 0..127
    const int h = bid & 1;         // k-half

    // stage: sum the two K-half partials; dl swizzled, bl linear
    {
        int isB = tid >> 8, i4 = tid & 255;
        const float4* s0 = (const float4*)(Ppart + (size_t)(isB ? 128 + r : r) * 1024);
        const float4* s1 = (const float4*)(Ppart + 262144 + (size_t)(isB ? 128 + r : r) * 1024);
        float4 a = s0[i4], b = s1[i4];
        float4 v = make_float4(a.x + b.x, a.y + b.y, a.z + b.z, a.w + b.w);
        if (isB) ((float4*)bl)[i4] = v;
        else     ((float4*)dl)[i4 ^ ((i4 >> 3) & 7)] = v;
    }
    __syncthreads();

    const int jo = tid >> 6;       // wave index = j-eighth (bv stays uniform)
    const int t  = tid & 63;       // k-octet
    const int k0 = (h * 512 + t * 8 - jo * 128) & 1023;   // multiple of 8

#define RD(fidx) (((const float4*)dl)[(((fidx) >> 2) ^ ((((fidx) >> 2) >> 3) & 7))])

    float acc[8] = {0.f, 0.f, 0.f, 0.f, 0.f, 0.f, 0.f, 0.f};
    float4 A  = RD(k0);
    float4 Bv = RD((k0 + 4) & 1023);

    const float* bq = bl + jo * 128;
    #pragma unroll 4
    for (int jc = 0; jc < 128; jc += 4) {
        float4 bv = *(const float4*)&bq[jc];           // wave-uniform broadcast
        float4 Nv = RD((k0 - jc - 4) & 1023);
        acc[0] += bv.x * A.x;  acc[1] += bv.x * A.y;  acc[2] += bv.x * A.z;  acc[3] += bv.x * A.w;
        acc[4] += bv.x * Bv.x; acc[5] += bv.x * Bv.y; acc[6] += bv.x * Bv.z; acc[7] += bv.x * Bv.w;
        acc[0] += bv.y * Nv.w; acc[1] += bv.y * A.x;  acc[2] += bv.y * A.y;  acc[3] += bv.y * A.z;
        acc[4] += bv.y * A.w;  acc[5] += bv.y * Bv.x; acc[6] += bv.y * Bv.y; acc[7] += bv.y * Bv.z;
        acc[0] += bv.z * Nv.z; acc[1] += bv.z * Nv.w; acc[2] += bv.z * A.x;  acc[3] += bv.z * A.y;
        acc[4] += bv.z * A.z;  acc[5] += bv.z * A.w;  acc[6] += bv.z * Bv.x; acc[7] += bv.z * Bv.y;
        acc[0] += bv.w * Nv.y; acc[1] += bv.w * Nv.z; acc[2] += bv.w * Nv.w; acc[3] += bv.w * A.x;
        acc[4] += bv.w * A.y;  acc[5] += bv.w * A.z;  acc[6] += bv.w * A.w;  acc[7] += bv.w * Bv.x;
        Bv = A; A = Nv;
    }
#undef RD

    {
        float* rd = red + jo * 576 + t * 9;
        #pragma unroll
        for (int q = 0; q < 8; ++q) rd[q] = acc[q];
    }
    __syncthreads();
    {
        // output o = tid (one float each; 2 KB contiguous store per block)
        int tt = tid >> 3, qq = tid & 7;
        float s = 0.f;
        #pragma unroll
        for (int u = 0; u < 8; ++u) s += red[u * 576 + tt * 9 + qq];
        out[(size_t)r * 1024 + h * 512 + tid] = 2.f * s;
    }
}

extern "C" void kernel_launch(void* const* d_in, const int* in_sizes, int n_in,
                              void* d_out, int out_size, void* d_ws, size_t ws_size,
                              hipStream_t stream) {
    const float* des  = (const float*)d_in[0];
    const float* body = (const float*)d_in[1];
    const float* kmat = (const float*)d_in[2];
    float* Ppart = (float*)d_ws;   // 2 x 256 x 1024 fp32 = 2 MB

    gemm_kernel<<<512, 512, 0, stream>>>(des, body, kmat, Ppart);
    conv_kernel<<<256, 512, 0, stream>>>(Ppart, (float*)d_out);
}